// Round 1
// baseline (1210.018 us; speedup 1.0000x reference)
//
#include <hip/hip_runtime.h>
#include <math.h>

#define B_SZ 4
#define L_SEQ 1024
#define D_MODEL 256
#define D_INNER 512
#define D_STATE 16
#define DT_RANK 16
#define NDBC 48
#define N_ROW (B_SZ * L_SEQ)  // 4096

__device__ __forceinline__ float siluf(float v) { return v / (1.f + __expf(-v)); }

// ---------------------------------------------------------------------------
// Kernel 1: xz = x @ W_in.T ; split into xm (first 512) and silu(z) (last 512)
// A: (4096 x 256) rowmajor, B: (1024 x 256) rowmajor (NT gemm)
// grid: (N/64=16, M/64=64), block 256
// ---------------------------------------------------------------------------
__global__ __launch_bounds__(256) void gemm_xz_kernel(
    const float* __restrict__ x, const float* __restrict__ W_in,
    float* __restrict__ xm, float* __restrict__ zs) {
  __shared__ float As[32][65];
  __shared__ float Bs[32][65];
  const int t = threadIdx.x;
  const int tx = t & 15, ty = t >> 4;
  const int m0 = blockIdx.y * 64;
  const int j0 = blockIdx.x * 64;
  float acc[4][4] = {};
  for (int k0 = 0; k0 < D_MODEL; k0 += 32) {
#pragma unroll
    for (int r = 0; r < 8; ++r) {
      int idx = t + r * 256;
      int kk = idx & 31, m = idx >> 5;
      As[kk][m] = x[(m0 + m) * D_MODEL + k0 + kk];
    }
#pragma unroll
    for (int r = 0; r < 8; ++r) {
      int idx = t + r * 256;
      int kk = idx & 31, n = idx >> 5;
      Bs[kk][n] = W_in[(j0 + n) * D_MODEL + k0 + kk];
    }
    __syncthreads();
#pragma unroll
    for (int k = 0; k < 32; ++k) {
      float a[4], bb[4];
#pragma unroll
      for (int i = 0; i < 4; ++i) a[i] = As[k][ty * 4 + i];
#pragma unroll
      for (int j = 0; j < 4; ++j) bb[j] = Bs[k][tx * 4 + j];
#pragma unroll
      for (int i = 0; i < 4; ++i)
#pragma unroll
        for (int j = 0; j < 4; ++j) acc[i][j] = fmaf(a[i], bb[j], acc[i][j]);
    }
    __syncthreads();
  }
#pragma unroll
  for (int i = 0; i < 4; ++i) {
    int m = m0 + ty * 4 + i;
    int j = j0 + tx * 4;
    if (j < D_INNER) {
      float4 v = make_float4(acc[i][0], acc[i][1], acc[i][2], acc[i][3]);
      *reinterpret_cast<float4*>(&xm[m * D_INNER + j]) = v;
    } else {
      float4 v = make_float4(siluf(acc[i][0]), siluf(acc[i][1]),
                             siluf(acc[i][2]), siluf(acc[i][3]));
      *reinterpret_cast<float4*>(&zs[m * D_INNER + (j - D_INNER)]) = v;
    }
  }
}

// ---------------------------------------------------------------------------
// Kernel 2: depthwise causal conv + silu, with per-stream index maps fused.
// stream 0: identity, 1: reversed, 2: roll(-shift), 3: reversed(roll(-shift))
// xconv layout: [s][b*L + l'][d]
// grid: (L, 4 streams, B), block 512 (d)
// ---------------------------------------------------------------------------
__global__ __launch_bounds__(512) void conv_kernel(
    const float* __restrict__ xm, const float* __restrict__ c1w,
    const float* __restrict__ c1b, const float* __restrict__ c2w,
    const float* __restrict__ c2b, const int* __restrict__ shift_ptr,
    float* __restrict__ xconv) {
  const int d = threadIdx.x;
  const int lp = blockIdx.x;
  const int s = blockIdx.y;
  const int b = blockIdx.z;
  const int sh = ((shift_ptr[0] % L_SEQ) + L_SEQ) & (L_SEQ - 1);
  const float* w = (s < 2 ? c1w : c2w);
  const float* bias = (s < 2 ? c1b : c2b);
  float4 wv = reinterpret_cast<const float4*>(w)[d];
  float acc = bias[d];
  const float* xb = xm + b * L_SEQ * D_INNER;
#pragma unroll
  for (int k = 0; k < 4; ++k) {
    int j = lp - 3 + k;
    if (j < 0) continue;
    int src;
    if (s == 0)      src = j;
    else if (s == 1) src = L_SEQ - 1 - j;
    else if (s == 2) src = (j + sh) & (L_SEQ - 1);
    else             src = (L_SEQ - 1 - j + sh) & (L_SEQ - 1);
    float wk = (k == 0 ? wv.x : k == 1 ? wv.y : k == 2 ? wv.z : wv.w);
    acc = fmaf(xb[src * D_INNER + d], wk, acc);
  }
  xconv[((s * B_SZ + b) * L_SEQ + lp) * D_INNER + d] = siluf(acc);
}

// ---------------------------------------------------------------------------
// Kernel 3: dBC_s = xconv_s @ Wx.T  (M=4096, N=48, K=512), batched over s
// grid: (64, 4), block 256
// ---------------------------------------------------------------------------
__global__ __launch_bounds__(256) void gemm_dbc_kernel(
    const float* __restrict__ xconv, const float* __restrict__ Wx1,
    const float* __restrict__ Wx2, float* __restrict__ dbc) {
  __shared__ float As[32][65];
  __shared__ float Bs[32][49];
  const int s = blockIdx.y;
  const int m0 = blockIdx.x * 64;
  const float* A = xconv + (size_t)s * N_ROW * D_INNER;
  const float* Bw = (s < 2 ? Wx1 : Wx2);
  const int t = threadIdx.x;
  const int tx = t & 15, ty = t >> 4;
  float acc[4][3] = {};
  for (int k0 = 0; k0 < D_INNER; k0 += 32) {
#pragma unroll
    for (int r = 0; r < 8; ++r) {
      int idx = t + r * 256;
      int kk = idx & 31, m = idx >> 5;
      As[kk][m] = A[(m0 + m) * D_INNER + k0 + kk];
    }
#pragma unroll
    for (int r = 0; r < 6; ++r) {
      int idx = t + r * 256;
      int kk = idx & 31, n = idx >> 5;
      Bs[kk][n] = Bw[n * D_INNER + k0 + kk];
    }
    __syncthreads();
#pragma unroll
    for (int k = 0; k < 32; ++k) {
      float a[4], bb[3];
#pragma unroll
      for (int i = 0; i < 4; ++i) a[i] = As[k][ty * 4 + i];
#pragma unroll
      for (int j = 0; j < 3; ++j) bb[j] = Bs[k][tx * 3 + j];
#pragma unroll
      for (int i = 0; i < 4; ++i)
#pragma unroll
        for (int j = 0; j < 3; ++j) acc[i][j] = fmaf(a[i], bb[j], acc[i][j]);
    }
    __syncthreads();
  }
  float* C = dbc + (size_t)s * N_ROW * NDBC;
#pragma unroll
  for (int i = 0; i < 4; ++i) {
    int m = m0 + ty * 4 + i;
    int n = tx * 3;
    C[m * NDBC + n] = acc[i][0];
    C[m * NDBC + n + 1] = acc[i][1];
    C[m * NDBC + n + 2] = acc[i][2];
  }
}

// ---------------------------------------------------------------------------
// Kernel 4: selective scan. One block per (d, s, b). 512 threads:
// t = c*16 + n : chunk c in [0,32), state n in [0,16). Chunk length 32.
// Fuses: delta projection (Wdt dot via shfl reduce) + softplus, dA=exp(dt*A),
// chunked scan, y = sum_n h*C + D*x, * z. Output Y[s][b][d][l] (transposed).
// ---------------------------------------------------------------------------
__global__ __launch_bounds__(512, 4) void scan_kernel(
    const float* __restrict__ xconv, const float* __restrict__ dbc,
    const float* __restrict__ Wdt1, const float* __restrict__ bdt1,
    const float* __restrict__ Wdt2, const float* __restrict__ bdt2,
    const float* __restrict__ A_log, const float* __restrict__ Dp,
    const float* __restrict__ zs, float* __restrict__ Y) {
  const int d = blockIdx.x;
  const int s = blockIdx.y;
  const int b = blockIdx.z;
  const int t = threadIdx.x;
  const int c = t >> 4, n = t & 15;

  const float* Wdt = (s < 2 ? Wdt1 : Wdt2);
  const float* bdtp = (s < 2 ? bdt1 : bdt2);
  const float wdt = Wdt[d * DT_RANK + n];
  const float bdt = bdtp[d];
  const float Adn = -__expf(A_log[d * D_STATE + n]);
  const float Dd = Dp[d];
  const float* xc = xconv + ((size_t)s * N_ROW + b * L_SEQ) * D_INNER + d;
  const float* dr = dbc + ((size_t)s * N_ROW + b * L_SEQ) * NDBC;
  const float* zr = zs + (size_t)b * L_SEQ * D_INNER + d;

  float rdA[32], rdxB[32];
  float P = 1.f, S = 0.f;
  const int lbase = c * 32;
#pragma unroll
  for (int i = 0; i < 32; ++i) {
    int l = lbase + i;
    const float* row = dr + l * NDBC;
    float dtv = row[n];
    float Bv = row[DT_RANK + n];
    float xv = xc[l * D_INNER];
    float p = dtv * wdt;
    p += __shfl_xor(p, 1, 16);
    p += __shfl_xor(p, 2, 16);
    p += __shfl_xor(p, 4, 16);
    p += __shfl_xor(p, 8, 16);
    float u = p + bdt;
    float delta = fmaxf(u, 0.f) + log1pf(__expf(-fabsf(u)));
    float a = __expf(delta * Adn);
    float bx = delta * xv * Bv;
    rdA[i] = a;
    rdxB[i] = bx;
    P *= a;
    S = fmaf(a, S, bx);
  }
  __shared__ float sP[512], sS[512], sH[512];
  __shared__ float sY[L_SEQ];
  sP[t] = P;
  sS[t] = S;
  __syncthreads();
  if (t < 16) {
    float h = 0.f;
    for (int c2 = 0; c2 < 32; ++c2) {
      int j = c2 * 16 + t;
      float hn = fmaf(sP[j], h, sS[j]);
      sH[j] = h;
      h = hn;
    }
  }
  __syncthreads();
  float h = sH[t];
#pragma unroll
  for (int i = 0; i < 32; ++i) {
    int l = lbase + i;
    h = fmaf(rdA[i], h, rdxB[i]);
    float Cv = dr[l * NDBC + 2 * DT_RANK + n];
    float yp = h * Cv;
    yp += __shfl_xor(yp, 1, 16);
    yp += __shfl_xor(yp, 2, 16);
    yp += __shfl_xor(yp, 4, 16);
    yp += __shfl_xor(yp, 8, 16);
    if (n == 0) {
      float xv = xc[l * D_INNER];
      sY[l] = fmaf(Dd, xv, yp) * zr[l * D_INNER];
    }
  }
  __syncthreads();
  float* yo = Y + (((size_t)s * B_SZ + b) * D_INNER + d) * L_SEQ;
  yo[t] = sY[t];
  yo[t + 512] = sY[t + 512];
}

// ---------------------------------------------------------------------------
// Kernel 5: out = Ysum @ W_out.T with the 4-stream reverse/roll gather fused
// into the A-tile load. Y layout [s][b][d][l']. grid: (4, 64), block 256.
// ---------------------------------------------------------------------------
__global__ __launch_bounds__(256) void gemm_out_kernel(
    const float* __restrict__ Y, const float* __restrict__ W_out,
    const int* __restrict__ shift_ptr, float* __restrict__ out) {
  __shared__ float As[32][64];
  __shared__ float Bs[32][65];
  const int t = threadIdx.x;
  const int tx = t & 15, ty = t >> 4;
  const int m0 = blockIdx.y * 64;
  const int j0 = blockIdx.x * 64;
  const int b = m0 / L_SEQ;
  const int l0 = m0 & (L_SEQ - 1);
  const int sh = ((shift_ptr[0] % L_SEQ) + L_SEQ) & (L_SEQ - 1);
  float acc[4][4] = {};
  for (int k0 = 0; k0 < D_INNER; k0 += 32) {
#pragma unroll
    for (int r = 0; r < 8; ++r) {
      int idx = t + r * 256;
      int m = idx & 63, kk = idx >> 6;
      int l = l0 + m;
      int kd = k0 + kk;
      const float* y0 = Y + (((size_t)0 * B_SZ + b) * D_INNER + kd) * L_SEQ;
      const float* y1 = Y + (((size_t)1 * B_SZ + b) * D_INNER + kd) * L_SEQ;
      const float* y2 = Y + (((size_t)2 * B_SZ + b) * D_INNER + kd) * L_SEQ;
      const float* y3 = Y + (((size_t)3 * B_SZ + b) * D_INNER + kd) * L_SEQ;
      int lr = (l - sh + L_SEQ) & (L_SEQ - 1);
      As[kk][m] = y0[l] + y1[L_SEQ - 1 - l] + y2[lr] + y3[L_SEQ - 1 - lr];
    }
#pragma unroll
    for (int r = 0; r < 8; ++r) {
      int idx = t + r * 256;
      int kk = idx & 31, nn = idx >> 5;
      Bs[kk][nn] = W_out[(j0 + nn) * D_INNER + k0 + kk];
    }
    __syncthreads();
#pragma unroll
    for (int k = 0; k < 32; ++k) {
      float a[4], bb[4];
#pragma unroll
      for (int i = 0; i < 4; ++i) a[i] = As[k][ty * 4 + i];
#pragma unroll
      for (int j = 0; j < 4; ++j) bb[j] = Bs[k][tx * 4 + j];
#pragma unroll
      for (int i = 0; i < 4; ++i)
#pragma unroll
        for (int j = 0; j < 4; ++j) acc[i][j] = fmaf(a[i], bb[j], acc[i][j]);
    }
    __syncthreads();
  }
#pragma unroll
  for (int i = 0; i < 4; ++i) {
    int m = m0 + ty * 4 + i;
    float4 v = make_float4(acc[i][0], acc[i][1], acc[i][2], acc[i][3]);
    *reinterpret_cast<float4*>(&out[m * D_MODEL + j0 + tx * 4]) = v;
  }
}

// ---------------------------------------------------------------------------
extern "C" void kernel_launch(void* const* d_in, const int* in_sizes, int n_in,
                              void* d_out, int out_size, void* d_ws,
                              size_t ws_size, hipStream_t stream) {
  const float* x = (const float*)d_in[0];
  const float* W_in = (const float*)d_in[1];
  const float* c1w = (const float*)d_in[2];
  const float* c1b = (const float*)d_in[3];
  const float* c2w = (const float*)d_in[4];
  const float* c2b = (const float*)d_in[5];
  const float* Wx1 = (const float*)d_in[6];
  const float* Wx2 = (const float*)d_in[7];
  const float* Wdt1 = (const float*)d_in[8];
  const float* bdt1 = (const float*)d_in[9];
  const float* Wdt2 = (const float*)d_in[10];
  const float* bdt2 = (const float*)d_in[11];
  const float* A_log = (const float*)d_in[12];
  const float* Dp = (const float*)d_in[13];
  const float* W_out = (const float*)d_in[14];
  const int* shift = (const int*)d_in[15];
  float* out = (float*)d_out;

  float* ws = (float*)d_ws;
  float* xm = ws;                                 // 4096*512
  float* zs = xm + (size_t)N_ROW * D_INNER;       // 4096*512
  float* xconv = zs + (size_t)N_ROW * D_INNER;    // 4*4096*512
  float* dbc = xconv + (size_t)4 * N_ROW * D_INNER;  // 4*4096*48
  float* Y = dbc + (size_t)4 * N_ROW * NDBC;      // 4*4096*512

  gemm_xz_kernel<<<dim3(16, 64), 256, 0, stream>>>(x, W_in, xm, zs);
  conv_kernel<<<dim3(L_SEQ, 4, B_SZ), 512, 0, stream>>>(xm, c1w, c1b, c2w, c2b,
                                                        shift, xconv);
  gemm_dbc_kernel<<<dim3(64, 4), 256, 0, stream>>>(xconv, Wx1, Wx2, dbc);
  scan_kernel<<<dim3(D_INNER, 4, B_SZ), 512, 0, stream>>>(
      xconv, dbc, Wdt1, bdt1, Wdt2, bdt2, A_log, Dp, zs, Y);
  gemm_out_kernel<<<dim3(4, 64), 256, 0, stream>>>(Y, W_out, shift, out);
}

// Round 2
// 775.076 us; speedup vs baseline: 1.5612x; 1.5612x over previous
//
#include <hip/hip_runtime.h>
#include <math.h>

#define B_SZ 4
#define L_SEQ 1024
#define D_MODEL 256
#define D_INNER 512
#define D_STATE 16
#define DT_RANK 16
#define NDBC 48
#define N_ROW (B_SZ * L_SEQ)  // 4096

__device__ __forceinline__ float siluf(float v) { return v / (1.f + __expf(-v)); }

// ---------------------------------------------------------------------------
// Kernel 1: xz = x @ W_in.T ; split into xm (first 512) and silu(z) (last 512)
// ---------------------------------------------------------------------------
__global__ __launch_bounds__(256) void gemm_xz_kernel(
    const float* __restrict__ x, const float* __restrict__ W_in,
    float* __restrict__ xm, float* __restrict__ zs) {
  __shared__ float As[32][65];
  __shared__ float Bs[32][65];
  const int t = threadIdx.x;
  const int tx = t & 15, ty = t >> 4;
  const int m0 = blockIdx.y * 64;
  const int j0 = blockIdx.x * 64;
  float acc[4][4] = {};
  for (int k0 = 0; k0 < D_MODEL; k0 += 32) {
#pragma unroll
    for (int r = 0; r < 8; ++r) {
      int idx = t + r * 256;
      int kk = idx & 31, m = idx >> 5;
      As[kk][m] = x[(m0 + m) * D_MODEL + k0 + kk];
    }
#pragma unroll
    for (int r = 0; r < 8; ++r) {
      int idx = t + r * 256;
      int kk = idx & 31, n = idx >> 5;
      Bs[kk][n] = W_in[(j0 + n) * D_MODEL + k0 + kk];
    }
    __syncthreads();
#pragma unroll
    for (int k = 0; k < 32; ++k) {
      float a[4], bb[4];
#pragma unroll
      for (int i = 0; i < 4; ++i) a[i] = As[k][ty * 4 + i];
#pragma unroll
      for (int j = 0; j < 4; ++j) bb[j] = Bs[k][tx * 4 + j];
#pragma unroll
      for (int i = 0; i < 4; ++i)
#pragma unroll
        for (int j = 0; j < 4; ++j) acc[i][j] = fmaf(a[i], bb[j], acc[i][j]);
    }
    __syncthreads();
  }
#pragma unroll
  for (int i = 0; i < 4; ++i) {
    int m = m0 + ty * 4 + i;
    int j = j0 + tx * 4;
    if (j < D_INNER) {
      float4 v = make_float4(acc[i][0], acc[i][1], acc[i][2], acc[i][3]);
      *reinterpret_cast<float4*>(&xm[m * D_INNER + j]) = v;
    } else {
      float4 v = make_float4(siluf(acc[i][0]), siluf(acc[i][1]),
                             siluf(acc[i][2]), siluf(acc[i][3]));
      *reinterpret_cast<float4*>(&zs[m * D_INNER + (j - D_INNER)]) = v;
    }
  }
}

// ---------------------------------------------------------------------------
// Kernel 2: depthwise causal conv + silu, per-stream index maps fused.
// xconv layout: [s][b*L + l'][d]
// ---------------------------------------------------------------------------
__global__ __launch_bounds__(512) void conv_kernel(
    const float* __restrict__ xm, const float* __restrict__ c1w,
    const float* __restrict__ c1b, const float* __restrict__ c2w,
    const float* __restrict__ c2b, const int* __restrict__ shift_ptr,
    float* __restrict__ xconv) {
  const int d = threadIdx.x;
  const int lp = blockIdx.x;
  const int s = blockIdx.y;
  const int b = blockIdx.z;
  const int sh = ((shift_ptr[0] % L_SEQ) + L_SEQ) & (L_SEQ - 1);
  const float* w = (s < 2 ? c1w : c2w);
  const float* bias = (s < 2 ? c1b : c2b);
  float4 wv = reinterpret_cast<const float4*>(w)[d];
  float acc = bias[d];
  const float* xb = xm + b * L_SEQ * D_INNER;
#pragma unroll
  for (int k = 0; k < 4; ++k) {
    int j = lp - 3 + k;
    if (j < 0) continue;
    int src;
    if (s == 0)      src = j;
    else if (s == 1) src = L_SEQ - 1 - j;
    else if (s == 2) src = (j + sh) & (L_SEQ - 1);
    else             src = (L_SEQ - 1 - j + sh) & (L_SEQ - 1);
    float wk = (k == 0 ? wv.x : k == 1 ? wv.y : k == 2 ? wv.z : wv.w);
    acc = fmaf(xb[src * D_INNER + d], wk, acc);
  }
  xconv[((s * B_SZ + b) * L_SEQ + lp) * D_INNER + d] = siluf(acc);
}

// ---------------------------------------------------------------------------
// Kernel 3: dBC_s = xconv_s @ Wx.T  (M=4096, N=48, K=512), batched over s.
// Output routed into dtl [s][row][16] and bc [s][row][16] (float2: B,C).
// ---------------------------------------------------------------------------
__global__ __launch_bounds__(256) void gemm_dbc_kernel(
    const float* __restrict__ xconv, const float* __restrict__ Wx1,
    const float* __restrict__ Wx2, float* __restrict__ dtl,
    float2* __restrict__ bc) {
  __shared__ float As[32][65];
  __shared__ float Bs[32][49];
  const int s = blockIdx.y;
  const int m0 = blockIdx.x * 64;
  const float* A = xconv + (size_t)s * N_ROW * D_INNER;
  const float* Bw = (s < 2 ? Wx1 : Wx2);
  const int t = threadIdx.x;
  const int tx = t & 15, ty = t >> 4;
  float acc[4][3] = {};
  for (int k0 = 0; k0 < D_INNER; k0 += 32) {
#pragma unroll
    for (int r = 0; r < 8; ++r) {
      int idx = t + r * 256;
      int kk = idx & 31, m = idx >> 5;
      As[kk][m] = A[(m0 + m) * D_INNER + k0 + kk];
    }
#pragma unroll
    for (int r = 0; r < 6; ++r) {
      int idx = t + r * 256;
      int kk = idx & 31, n = idx >> 5;
      Bs[kk][n] = Bw[n * D_INNER + k0 + kk];
    }
    __syncthreads();
#pragma unroll
    for (int k = 0; k < 32; ++k) {
      float a[4], bb[3];
#pragma unroll
      for (int i = 0; i < 4; ++i) a[i] = As[k][ty * 4 + i];
#pragma unroll
      for (int j = 0; j < 3; ++j) bb[j] = Bs[k][tx * 3 + j];
#pragma unroll
      for (int i = 0; i < 4; ++i)
#pragma unroll
        for (int j = 0; j < 3; ++j) acc[i][j] = fmaf(a[i], bb[j], acc[i][j]);
    }
    __syncthreads();
  }
  float* dtlC = dtl + (size_t)s * N_ROW * DT_RANK;
  float2* bcC = bc + (size_t)s * N_ROW * D_STATE;
#pragma unroll
  for (int i = 0; i < 4; ++i) {
    int m = m0 + ty * 4 + i;
#pragma unroll
    for (int jj = 0; jj < 3; ++jj) {
      int n = tx * 3 + jj;
      float v = acc[i][jj];
      if (n < DT_RANK) dtlC[m * DT_RANK + n] = v;
      else if (n < DT_RANK + D_STATE) bcC[m * D_STATE + (n - DT_RANK)].x = v;
      else bcC[m * D_STATE + (n - DT_RANK - D_STATE)].y = v;
    }
  }
}

// ---------------------------------------------------------------------------
// Kernel 4: selective scan, serial over l, NO per-thread arrays.
// One block = 32 d x 16 n for one (s,b). 16384 lanes/(s,b) * 16 = 131072
// chains -> 2048 waves. Manual 4-step prefetch (static indices only).
// Fuses delta projection (shfl dot over n) + softplus + dA + scan + y + z.
// Output Y[s][b][d][l].
// ---------------------------------------------------------------------------
__global__ __launch_bounds__(512) void scan_kernel(
    const float* __restrict__ xconv, const float* __restrict__ dtl,
    const float2* __restrict__ bc, const float* __restrict__ Wdt1,
    const float* __restrict__ bdt1, const float* __restrict__ Wdt2,
    const float* __restrict__ bdt2, const float* __restrict__ A_log,
    const float* __restrict__ Dp, const float* __restrict__ zs,
    float* __restrict__ Y) {
  const int t = threadIdx.x;
  const int j = t >> 4, n = t & 15;
  const int d0 = blockIdx.x * 32;
  const int s = blockIdx.y;
  const int b = blockIdx.z;
  const int d = d0 + j;

  const float* Wdt = (s < 2 ? Wdt1 : Wdt2);
  const float* bdtp = (s < 2 ? bdt1 : bdt2);
  const float wdt = Wdt[d * DT_RANK + n];
  const float bdt = bdtp[d];
  const float Adn = -__expf(A_log[d * D_STATE + n]);
  const float Dd = Dp[d];

  const size_t srow = ((size_t)s * B_SZ + b) * L_SEQ;
  const float* dtlp = dtl + srow * DT_RANK + n;           // [l]*16
  const float2* bcp = bc + srow * D_STATE + n;            // [l]*16
  const float* xcp = xconv + srow * D_INNER + d;          // [l]*512
  const float* zp = zs + ((size_t)b * L_SEQ) * D_INNER + d;  // [l]*512
  float* yo = Y + (((size_t)s * B_SZ + b) * D_INNER + d) * L_SEQ;

  float c_dt[4], c_xv[4];
  float2 c_bc[4];
#pragma unroll
  for (int u = 0; u < 4; ++u) {
    c_dt[u] = dtlp[u * DT_RANK];
    c_bc[u] = bcp[u * D_STATE];
    c_xv[u] = xcp[(size_t)u * D_INNER];
  }
  float h = 0.f;
  for (int lt = 0; lt < L_SEQ; lt += 4) {
    float n_dt[4], n_xv[4];
    float2 n_bc[4];
    const int lb = (lt + 4 < L_SEQ) ? lt + 4 : lt;  // clamp: last iter reloads
#pragma unroll
    for (int u = 0; u < 4; ++u) {
      int l = lb + u;
      n_dt[u] = dtlp[(size_t)l * DT_RANK];
      n_bc[u] = bcp[(size_t)l * D_STATE];
      n_xv[u] = xcp[(size_t)l * D_INNER];
    }
#pragma unroll
    for (int u = 0; u < 4; ++u) {
      int l = lt + u;
      float p = c_dt[u] * wdt;
      p += __shfl_xor(p, 1, 16);
      p += __shfl_xor(p, 2, 16);
      p += __shfl_xor(p, 4, 16);
      p += __shfl_xor(p, 8, 16);
      float uu = p + bdt;
      float delta = fmaxf(uu, 0.f) + __logf(1.f + __expf(-fabsf(uu)));
      float a = __expf(delta * Adn);
      float dx = delta * c_xv[u];
      h = fmaf(a, h, dx * c_bc[u].x);
      float yp = h * c_bc[u].y;
      yp += __shfl_xor(yp, 1, 16);
      yp += __shfl_xor(yp, 2, 16);
      yp += __shfl_xor(yp, 4, 16);
      yp += __shfl_xor(yp, 8, 16);
      if (n == 0) {
        yo[l] = (yp + Dd * c_xv[u]) * zp[(size_t)l * D_INNER];
      }
    }
#pragma unroll
    for (int u = 0; u < 4; ++u) {
      c_dt[u] = n_dt[u];
      c_bc[u] = n_bc[u];
      c_xv[u] = n_xv[u];
    }
  }
}

// ---------------------------------------------------------------------------
// Kernel 5: out = Ysum @ W_out.T with 4-stream reverse/roll gather fused.
// ---------------------------------------------------------------------------
__global__ __launch_bounds__(256) void gemm_out_kernel(
    const float* __restrict__ Y, const float* __restrict__ W_out,
    const int* __restrict__ shift_ptr, float* __restrict__ out) {
  __shared__ float As[32][64];
  __shared__ float Bs[32][65];
  const int t = threadIdx.x;
  const int tx = t & 15, ty = t >> 4;
  const int m0 = blockIdx.y * 64;
  const int j0 = blockIdx.x * 64;
  const int b = m0 / L_SEQ;
  const int l0 = m0 & (L_SEQ - 1);
  const int sh = ((shift_ptr[0] % L_SEQ) + L_SEQ) & (L_SEQ - 1);
  float acc[4][4] = {};
  for (int k0 = 0; k0 < D_INNER; k0 += 32) {
#pragma unroll
    for (int r = 0; r < 8; ++r) {
      int idx = t + r * 256;
      int m = idx & 63, kk = idx >> 6;
      int l = l0 + m;
      int kd = k0 + kk;
      const float* y0 = Y + (((size_t)0 * B_SZ + b) * D_INNER + kd) * L_SEQ;
      const float* y1 = Y + (((size_t)1 * B_SZ + b) * D_INNER + kd) * L_SEQ;
      const float* y2 = Y + (((size_t)2 * B_SZ + b) * D_INNER + kd) * L_SEQ;
      const float* y3 = Y + (((size_t)3 * B_SZ + b) * D_INNER + kd) * L_SEQ;
      int lr = (l - sh + L_SEQ) & (L_SEQ - 1);
      As[kk][m] = y0[l] + y1[L_SEQ - 1 - l] + y2[lr] + y3[L_SEQ - 1 - lr];
    }
#pragma unroll
    for (int r = 0; r < 8; ++r) {
      int idx = t + r * 256;
      int kk = idx & 31, nn = idx >> 5;
      Bs[kk][nn] = W_out[(j0 + nn) * D_INNER + k0 + kk];
    }
    __syncthreads();
#pragma unroll
    for (int k = 0; k < 32; ++k) {
      float a[4], bb[4];
#pragma unroll
      for (int i = 0; i < 4; ++i) a[i] = As[k][ty * 4 + i];
#pragma unroll
      for (int j = 0; j < 4; ++j) bb[j] = Bs[k][tx * 4 + j];
#pragma unroll
      for (int i = 0; i < 4; ++i)
#pragma unroll
        for (int j = 0; j < 4; ++j) acc[i][j] = fmaf(a[i], bb[j], acc[i][j]);
    }
    __syncthreads();
  }
#pragma unroll
  for (int i = 0; i < 4; ++i) {
    int m = m0 + ty * 4 + i;
    float4 v = make_float4(acc[i][0], acc[i][1], acc[i][2], acc[i][3]);
    *reinterpret_cast<float4*>(&out[m * D_MODEL + j0 + tx * 4]) = v;
  }
}

// ---------------------------------------------------------------------------
extern "C" void kernel_launch(void* const* d_in, const int* in_sizes, int n_in,
                              void* d_out, int out_size, void* d_ws,
                              size_t ws_size, hipStream_t stream) {
  const float* x = (const float*)d_in[0];
  const float* W_in = (const float*)d_in[1];
  const float* c1w = (const float*)d_in[2];
  const float* c1b = (const float*)d_in[3];
  const float* c2w = (const float*)d_in[4];
  const float* c2b = (const float*)d_in[5];
  const float* Wx1 = (const float*)d_in[6];
  const float* Wx2 = (const float*)d_in[7];
  const float* Wdt1 = (const float*)d_in[8];
  const float* bdt1 = (const float*)d_in[9];
  const float* Wdt2 = (const float*)d_in[10];
  const float* bdt2 = (const float*)d_in[11];
  const float* A_log = (const float*)d_in[12];
  const float* Dp = (const float*)d_in[13];
  const float* W_out = (const float*)d_in[14];
  const int* shift = (const int*)d_in[15];
  float* out = (float*)d_out;

  float* ws = (float*)d_ws;
  float* xm = ws;                                    // 2M floats
  float* zs = xm + (size_t)N_ROW * D_INNER;          // 2M
  float* xconv = zs + (size_t)N_ROW * D_INNER;       // 8M
  float* dtl = xconv + (size_t)4 * N_ROW * D_INNER;  // 256K
  float* bcf = dtl + (size_t)4 * N_ROW * DT_RANK;    // 512K (as float2: 256K)
  float* Y = bcf + (size_t)4 * N_ROW * D_STATE * 2;  // 8M
  float2* bc = (float2*)bcf;

  gemm_xz_kernel<<<dim3(16, 64), 256, 0, stream>>>(x, W_in, xm, zs);
  conv_kernel<<<dim3(L_SEQ, 4, B_SZ), 512, 0, stream>>>(xm, c1w, c1b, c2w, c2b,
                                                        shift, xconv);
  gemm_dbc_kernel<<<dim3(64, 4), 256, 0, stream>>>(xconv, Wx1, Wx2, dtl, bc);
  scan_kernel<<<dim3(16, 4, B_SZ), 512, 0, stream>>>(
      xconv, dtl, bc, Wdt1, bdt1, Wdt2, bdt2, A_log, Dp, zs, Y);
  gemm_out_kernel<<<dim3(4, 64), 256, 0, stream>>>(Y, W_out, shift, out);
}

// Round 5
// 257.637 us; speedup vs baseline: 4.6966x; 3.0084x over previous
//
#include <hip/hip_runtime.h>
#include <math.h>

#define B_SZ 4
#define L_SEQ 1024
#define D_MODEL 256
#define D_INNER 512
#define D_STATE 16
#define DT_RANK 16
#define NDBC 48
#define N_ROW (B_SZ * L_SEQ)  // 4096

#define CHUNKS 32
#define LC (L_SEQ / CHUNKS)  // 32

__device__ __forceinline__ float siluf(float v) { return v / (1.f + __expf(-v)); }
__device__ __forceinline__ float softplusf(float u) {
  return fmaxf(u, 0.f) + __logf(1.f + __expf(-fabsf(u)));
}

// load 16 consecutive floats (64B-aligned) into named regs via 4x float4
#define LOAD16(dst, ptr, l)                                                  \
  {                                                                          \
    float4 q0 = (ptr)[(l) * 4 + 0], q1 = (ptr)[(l) * 4 + 1],                 \
           q2 = (ptr)[(l) * 4 + 2], q3 = (ptr)[(l) * 4 + 3];                 \
    dst[0] = q0.x; dst[1] = q0.y; dst[2] = q0.z; dst[3] = q0.w;              \
    dst[4] = q1.x; dst[5] = q1.y; dst[6] = q1.z; dst[7] = q1.w;              \
    dst[8] = q2.x; dst[9] = q2.y; dst[10] = q2.z; dst[11] = q2.w;            \
    dst[12] = q3.x; dst[13] = q3.y; dst[14] = q3.z; dst[15] = q3.w;          \
  }

// ---------------------------------------------------------------------------
// Kernel 1: xz = x @ W_in.T ; split into xm (first 512) and silu(z) (last 512)
// ---------------------------------------------------------------------------
__global__ __launch_bounds__(256) void gemm_xz_kernel(
    const float* __restrict__ x, const float* __restrict__ W_in,
    float* __restrict__ xm, float* __restrict__ zs) {
  __shared__ float As[32][65];
  __shared__ float Bs[32][65];
  const int t = threadIdx.x;
  const int tx = t & 15, ty = t >> 4;
  const int m0 = blockIdx.y * 64;
  const int j0 = blockIdx.x * 64;
  float acc[4][4] = {};
  for (int k0 = 0; k0 < D_MODEL; k0 += 32) {
#pragma unroll
    for (int r = 0; r < 8; ++r) {
      int idx = t + r * 256;
      int kk = idx & 31, m = idx >> 5;
      As[kk][m] = x[(m0 + m) * D_MODEL + k0 + kk];
    }
#pragma unroll
    for (int r = 0; r < 8; ++r) {
      int idx = t + r * 256;
      int kk = idx & 31, n = idx >> 5;
      Bs[kk][n] = W_in[(j0 + n) * D_MODEL + k0 + kk];
    }
    __syncthreads();
#pragma unroll
    for (int k = 0; k < 32; ++k) {
      float a[4], bb[4];
#pragma unroll
      for (int i = 0; i < 4; ++i) a[i] = As[k][ty * 4 + i];
#pragma unroll
      for (int j = 0; j < 4; ++j) bb[j] = Bs[k][tx * 4 + j];
#pragma unroll
      for (int i = 0; i < 4; ++i)
#pragma unroll
        for (int j = 0; j < 4; ++j) acc[i][j] = fmaf(a[i], bb[j], acc[i][j]);
    }
    __syncthreads();
  }
#pragma unroll
  for (int i = 0; i < 4; ++i) {
    int m = m0 + ty * 4 + i;
    int j = j0 + tx * 4;
    if (j < D_INNER) {
      float4 v = make_float4(acc[i][0], acc[i][1], acc[i][2], acc[i][3]);
      *reinterpret_cast<float4*>(&xm[m * D_INNER + j]) = v;
    } else {
      float4 v = make_float4(siluf(acc[i][0]), siluf(acc[i][1]),
                             siluf(acc[i][2]), siluf(acc[i][3]));
      *reinterpret_cast<float4*>(&zs[m * D_INNER + (j - D_INNER)]) = v;
    }
  }
}

// ---------------------------------------------------------------------------
// Kernel 2: depthwise causal conv + silu, per-stream index maps fused.
// xconv layout: [s][b*L + l'][d]
// ---------------------------------------------------------------------------
__global__ __launch_bounds__(512) void conv_kernel(
    const float* __restrict__ xm, const float* __restrict__ c1w,
    const float* __restrict__ c1b, const float* __restrict__ c2w,
    const float* __restrict__ c2b, const int* __restrict__ shift_ptr,
    float* __restrict__ xconv) {
  const int d = threadIdx.x;
  const int lp = blockIdx.x;
  const int s = blockIdx.y;
  const int b = blockIdx.z;
  const int sh = ((shift_ptr[0] % L_SEQ) + L_SEQ) & (L_SEQ - 1);
  const float* w = (s < 2 ? c1w : c2w);
  const float* bias = (s < 2 ? c1b : c2b);
  float4 wv = reinterpret_cast<const float4*>(w)[d];
  float acc = bias[d];
  const float* xb = xm + b * L_SEQ * D_INNER;
#pragma unroll
  for (int k = 0; k < 4; ++k) {
    int j = lp - 3 + k;
    if (j < 0) continue;
    int src;
    if (s == 0)      src = j;
    else if (s == 1) src = L_SEQ - 1 - j;
    else if (s == 2) src = (j + sh) & (L_SEQ - 1);
    else             src = (L_SEQ - 1 - j + sh) & (L_SEQ - 1);
    float wk = (k == 0 ? wv.x : k == 1 ? wv.y : k == 2 ? wv.z : wv.w);
    acc = fmaf(xb[src * D_INNER + d], wk, acc);
  }
  xconv[((s * B_SZ + b) * L_SEQ + lp) * D_INNER + d] = siluf(acc);
}

// ---------------------------------------------------------------------------
// Kernel 3: dBC_s = xconv_s @ Wx.T  (M=4096, N=48, K=512), batched over s.
// Outputs split into dtl / Bv / Cv, each [s][row][16] (64B rows).
// ---------------------------------------------------------------------------
__global__ __launch_bounds__(256) void gemm_dbc_kernel(
    const float* __restrict__ xconv, const float* __restrict__ Wx1,
    const float* __restrict__ Wx2, float* __restrict__ dtl,
    float* __restrict__ Bv, float* __restrict__ Cv) {
  __shared__ float As[32][65];
  __shared__ float Bs[32][49];
  const int s = blockIdx.y;
  const int m0 = blockIdx.x * 64;
  const float* A = xconv + (size_t)s * N_ROW * D_INNER;
  const float* Bw = (s < 2 ? Wx1 : Wx2);
  const int t = threadIdx.x;
  const int tx = t & 15, ty = t >> 4;
  float acc[4][3] = {};
  for (int k0 = 0; k0 < D_INNER; k0 += 32) {
#pragma unroll
    for (int r = 0; r < 8; ++r) {
      int idx = t + r * 256;
      int kk = idx & 31, m = idx >> 5;
      As[kk][m] = A[(m0 + m) * D_INNER + k0 + kk];
    }
#pragma unroll
    for (int r = 0; r < 6; ++r) {
      int idx = t + r * 256;
      int kk = idx & 31, n = idx >> 5;
      Bs[kk][n] = Bw[n * D_INNER + k0 + kk];
    }
    __syncthreads();
#pragma unroll
    for (int k = 0; k < 32; ++k) {
      float a[4], bb[3];
#pragma unroll
      for (int i = 0; i < 4; ++i) a[i] = As[k][ty * 4 + i];
#pragma unroll
      for (int j = 0; j < 3; ++j) bb[j] = Bs[k][tx * 3 + j];
#pragma unroll
      for (int i = 0; i < 4; ++i)
#pragma unroll
        for (int j = 0; j < 3; ++j) acc[i][j] = fmaf(a[i], bb[j], acc[i][j]);
    }
    __syncthreads();
  }
  float* dtlC = dtl + (size_t)s * N_ROW * DT_RANK;
  float* BvC = Bv + (size_t)s * N_ROW * D_STATE;
  float* CvC = Cv + (size_t)s * N_ROW * D_STATE;
#pragma unroll
  for (int i = 0; i < 4; ++i) {
    int m = m0 + ty * 4 + i;
#pragma unroll
    for (int jj = 0; jj < 3; ++jj) {
      int n = tx * 3 + jj;
      float v = acc[i][jj];
      if (n < DT_RANK) dtlC[m * DT_RANK + n] = v;
      else if (n < DT_RANK + D_STATE) BvC[m * D_STATE + (n - DT_RANK)] = v;
      else CvC[m * D_STATE + (n - DT_RANK - D_STATE)] = v;
    }
  }
}

// ---------------------------------------------------------------------------
// Kernel 4: selective scan, chunked two-pass (recompute), lane-local states.
// Block = 512 threads: dd = t&15 (d within a 16-wide d-tile), c = t>>4
// (chunk of 32 l-steps). Each thread holds 16 n-states in registers; dt
// projection is an in-lane 16-FMA dot (no cross-lane ops in hot loop).
// Pass 1: per-chunk (P[16],S[16]) -> LDS; in-block serial combine; Pass 2:
// re-walk with h0, emit y. Grid (32 d-tiles, 4 s, 4 b) = 512 blocks.
// ---------------------------------------------------------------------------
__global__ __launch_bounds__(512, 4) void scan_kernel(
    const float* __restrict__ xconv, const float* __restrict__ dtl,
    const float* __restrict__ Bvv, const float* __restrict__ Cvv,
    const float* __restrict__ Wdt1, const float* __restrict__ bdt1,
    const float* __restrict__ Wdt2, const float* __restrict__ bdt2,
    const float* __restrict__ A_log, const float* __restrict__ Dp,
    const float* __restrict__ zs, float* __restrict__ Y) {
  __shared__ float sP[16][512];
  __shared__ float sS[16][512];
  const int t = threadIdx.x;
  const int dd = t & 15;
  const int c = t >> 4;
  const int d = blockIdx.x * 16 + dd;
  const int s = blockIdx.y;
  const int b = blockIdx.z;

  const float* Wdt = (s < 2 ? Wdt1 : Wdt2);
  const float bdt = (s < 2 ? bdt1 : bdt2)[d];
  const float Dd = Dp[d];

  float w[16], A[16];
  LOAD16(w, reinterpret_cast<const float4*>(Wdt), d);
  {
    float al[16];
    LOAD16(al, reinterpret_cast<const float4*>(A_log), d);
#pragma unroll
    for (int n = 0; n < 16; ++n) A[n] = -__expf(al[n]);
  }

  const size_t srow = ((size_t)s * B_SZ + b) * L_SEQ;
  const float4* dtp = reinterpret_cast<const float4*>(dtl + srow * DT_RANK);
  const float4* Bp = reinterpret_cast<const float4*>(Bvv + srow * D_STATE);
  const float4* Cp = reinterpret_cast<const float4*>(Cvv + srow * D_STATE);
  const float* xcp = xconv + srow * D_INNER + d;
  const float* zp = zs + (size_t)b * L_SEQ * D_INNER + d;
  float* yo = Y + (((size_t)s * B_SZ + b) * D_INNER + d) * L_SEQ;

  const int lbase = c * LC;

  // ---- Pass 1: per-chunk (P, S) ----
  float P[16], S[16];
#pragma unroll
  for (int n = 0; n < 16; ++n) { P[n] = 1.f; S[n] = 0.f; }
#pragma unroll 4
  for (int i = 0; i < LC; ++i) {
    const int l = lbase + i;
    float dt[16], Bf[16];
    LOAD16(dt, dtp, l);
    LOAD16(Bf, Bp, l);
    float xv = xcp[(size_t)l * D_INNER];
    float p0 = dt[0] * w[0], p1 = dt[4] * w[4], p2 = dt[8] * w[8],
          p3 = dt[12] * w[12];
#pragma unroll
    for (int r = 1; r < 4; ++r) {
      p0 = fmaf(dt[r], w[r], p0);
      p1 = fmaf(dt[4 + r], w[4 + r], p1);
      p2 = fmaf(dt[8 + r], w[8 + r], p2);
      p3 = fmaf(dt[12 + r], w[12 + r], p3);
    }
    float delta = softplusf(((p0 + p1) + (p2 + p3)) + bdt);
    float dx = delta * xv;
#pragma unroll
    for (int n = 0; n < 16; ++n) {
      float a = __expf(delta * A[n]);
      P[n] *= a;
      S[n] = fmaf(a, S[n], dx * Bf[n]);
    }
  }
#pragma unroll
  for (int n = 0; n < 16; ++n) {
    sP[dd][c * 16 + n] = P[n];
    sS[dd][c * 16 + n] = S[n];
  }
  __syncthreads();

  // ---- Combine: serial over chunks; h0 for chunk c left in sP slot ----
  if (t < 256) {
    const int dd2 = t >> 4, n2 = t & 15;
    float h = 0.f;
    for (int c2 = 0; c2 < CHUNKS; ++c2) {
      const int idx = c2 * 16 + n2;
      float Pv = sP[dd2][idx];
      float Sv = sS[dd2][idx];
      sP[dd2][idx] = h;
      h = fmaf(Pv, h, Sv);
    }
  }
  __syncthreads();

  // ---- Pass 2: re-walk with h0, emit y ----
  float h[16];
#pragma unroll
  for (int n = 0; n < 16; ++n) h[n] = sP[dd][c * 16 + n];
#pragma unroll 4
  for (int i = 0; i < LC; ++i) {
    const int l = lbase + i;
    float dt[16], Bf[16], Cf[16];
    LOAD16(dt, dtp, l);
    LOAD16(Bf, Bp, l);
    LOAD16(Cf, Cp, l);
    float xv = xcp[(size_t)l * D_INNER];
    float zl = zp[(size_t)l * D_INNER];
    float p0 = dt[0] * w[0], p1 = dt[4] * w[4], p2 = dt[8] * w[8],
          p3 = dt[12] * w[12];
#pragma unroll
    for (int r = 1; r < 4; ++r) {
      p0 = fmaf(dt[r], w[r], p0);
      p1 = fmaf(dt[4 + r], w[4 + r], p1);
      p2 = fmaf(dt[8 + r], w[8 + r], p2);
      p3 = fmaf(dt[12 + r], w[12 + r], p3);
    }
    float delta = softplusf(((p0 + p1) + (p2 + p3)) + bdt);
    float dx = delta * xv;
    float y0 = 0.f, y1 = 0.f, y2 = 0.f, y3 = 0.f;
#pragma unroll
    for (int n = 0; n < 4; ++n) {
      float a0 = __expf(delta * A[n]);
      float a1 = __expf(delta * A[4 + n]);
      float a2 = __expf(delta * A[8 + n]);
      float a3 = __expf(delta * A[12 + n]);
      h[n] = fmaf(a0, h[n], dx * Bf[n]);
      h[4 + n] = fmaf(a1, h[4 + n], dx * Bf[4 + n]);
      h[8 + n] = fmaf(a2, h[8 + n], dx * Bf[8 + n]);
      h[12 + n] = fmaf(a3, h[12 + n], dx * Bf[12 + n]);
      y0 = fmaf(h[n], Cf[n], y0);
      y1 = fmaf(h[4 + n], Cf[4 + n], y1);
      y2 = fmaf(h[8 + n], Cf[8 + n], y2);
      y3 = fmaf(h[12 + n], Cf[12 + n], y3);
    }
    float y = (y0 + y1) + (y2 + y3);
    yo[l] = fmaf(Dd, xv, y) * zl;
  }
}

// ---------------------------------------------------------------------------
// Kernel 5: out = Ysum @ W_out.T with 4-stream reverse/roll gather fused.
// ---------------------------------------------------------------------------
__global__ __launch_bounds__(256) void gemm_out_kernel(
    const float* __restrict__ Y, const float* __restrict__ W_out,
    const int* __restrict__ shift_ptr, float* __restrict__ out) {
  __shared__ float As[32][64];
  __shared__ float Bs[32][65];
  const int t = threadIdx.x;
  const int tx = t & 15, ty = t >> 4;
  const int m0 = blockIdx.y * 64;
  const int j0 = blockIdx.x * 64;
  const int b = m0 / L_SEQ;
  const int l0 = m0 & (L_SEQ - 1);
  const int sh = ((shift_ptr[0] % L_SEQ) + L_SEQ) & (L_SEQ - 1);
  float acc[4][4] = {};
  for (int k0 = 0; k0 < D_INNER; k0 += 32) {
#pragma unroll
    for (int r = 0; r < 8; ++r) {
      int idx = t + r * 256;
      int m = idx & 63, kk = idx >> 6;
      int l = l0 + m;
      int kd = k0 + kk;
      const float* y0 = Y + (((size_t)0 * B_SZ + b) * D_INNER + kd) * L_SEQ;
      const float* y1 = Y + (((size_t)1 * B_SZ + b) * D_INNER + kd) * L_SEQ;
      const float* y2 = Y + (((size_t)2 * B_SZ + b) * D_INNER + kd) * L_SEQ;
      const float* y3 = Y + (((size_t)3 * B_SZ + b) * D_INNER + kd) * L_SEQ;
      int lr = (l - sh + L_SEQ) & (L_SEQ - 1);
      As[kk][m] = y0[l] + y1[L_SEQ - 1 - l] + y2[lr] + y3[L_SEQ - 1 - lr];
    }
#pragma unroll
    for (int r = 0; r < 8; ++r) {
      int idx = t + r * 256;
      int kk = idx & 31, nn = idx >> 5;
      Bs[kk][nn] = W_out[(j0 + nn) * D_INNER + k0 + kk];
    }
    __syncthreads();
#pragma unroll
    for (int k = 0; k < 32; ++k) {
      float a[4], bb[4];
#pragma unroll
      for (int i = 0; i < 4; ++i) a[i] = As[k][ty * 4 + i];
#pragma unroll
      for (int j = 0; j < 4; ++j) bb[j] = Bs[k][tx * 4 + j];
#pragma unroll
      for (int i = 0; i < 4; ++i)
#pragma unroll
        for (int j = 0; j < 4; ++j) acc[i][j] = fmaf(a[i], bb[j], acc[i][j]);
    }
    __syncthreads();
  }
#pragma unroll
  for (int i = 0; i < 4; ++i) {
    int m = m0 + ty * 4 + i;
    float4 v = make_float4(acc[i][0], acc[i][1], acc[i][2], acc[i][3]);
    *reinterpret_cast<float4*>(&out[m * D_MODEL + j0 + tx * 4]) = v;
  }
}

// ---------------------------------------------------------------------------
extern "C" void kernel_launch(void* const* d_in, const int* in_sizes, int n_in,
                              void* d_out, int out_size, void* d_ws,
                              size_t ws_size, hipStream_t stream) {
  const float* x = (const float*)d_in[0];
  const float* W_in = (const float*)d_in[1];
  const float* c1w = (const float*)d_in[2];
  const float* c1b = (const float*)d_in[3];
  const float* c2w = (const float*)d_in[4];
  const float* c2b = (const float*)d_in[5];
  const float* Wx1 = (const float*)d_in[6];
  const float* Wx2 = (const float*)d_in[7];
  const float* Wdt1 = (const float*)d_in[8];
  const float* bdt1 = (const float*)d_in[9];
  const float* Wdt2 = (const float*)d_in[10];
  const float* bdt2 = (const float*)d_in[11];
  const float* A_log = (const float*)d_in[12];
  const float* Dp = (const float*)d_in[13];
  const float* W_out = (const float*)d_in[14];
  const int* shift = (const int*)d_in[15];
  float* out = (float*)d_out;

  float* ws = (float*)d_ws;
  float* xm = ws;                                    // 2M floats
  float* zs = xm + (size_t)N_ROW * D_INNER;          // 2M
  float* xconv = zs + (size_t)N_ROW * D_INNER;       // 8M
  float* dtl = xconv + (size_t)4 * N_ROW * D_INNER;  // 256K
  float* Bv = dtl + (size_t)4 * N_ROW * DT_RANK;     // 256K
  float* Cv = Bv + (size_t)4 * N_ROW * D_STATE;      // 256K
  float* Y = Cv + (size_t)4 * N_ROW * D_STATE;       // 8M

  gemm_xz_kernel<<<dim3(16, 64), 256, 0, stream>>>(x, W_in, xm, zs);
  conv_kernel<<<dim3(L_SEQ, 4, B_SZ), 512, 0, stream>>>(xm, c1w, c1b, c2w, c2b,
                                                        shift, xconv);
  gemm_dbc_kernel<<<dim3(64, 4), 256, 0, stream>>>(xconv, Wx1, Wx2, dtl, Bv,
                                                   Cv);
  scan_kernel<<<dim3(32, 4, 4), 512, 0, stream>>>(
      xconv, dtl, Bv, Cv, Wdt1, bdt1, Wdt2, bdt2, A_log, Dp, zs, Y);
  gemm_out_kernel<<<dim3(4, 64), 256, 0, stream>>>(Y, W_out, shift, out);
}